// Round 4
// baseline (154.760 us; speedup 1.0000x reference)
//
#include <hip/hip_runtime.h>
#include <math.h>

#define HH 512
#define WW 1024
#define RR 5
#define KK 11
#define TOPK 200
#define MAXC 16384

#define BW 64            // vote tile width
#define BH 8             // vote tile height
#define TT 2             // outputs per thread (column)
#define SROWS (BH + 10)  // 18 staged rows
#define SCOLS (BW + 10)  // 74 staged cols

// ws layout (bytes):
// [0..63]          : meta ints: meta[0]=cnt, meta[1]=Mtop, meta[2]=anyv, meta[3]=done
// [64 ..)          : vote float[H*W]
// [64+4*HW ..)     : cv float[MAXC]
// [.. +4*MAXC ..)  : ci int[MAXC]
// [.. +4*MAXC ..)  : selx float[TOPK], sely float[TOPK]

__global__ __launch_bounds__(256) void vote_kernel(const float* __restrict__ cr,
                                                   float* __restrict__ vote,
                                                   int* __restrict__ meta) {
    __shared__ float2 s[SROWS][BW + 16];   // padded to 80 float2/row
    const int tid = threadIdx.x;
    const int bx = blockIdx.x * BW, by = blockIdx.y * BH;

    if (bx == 0 && by == 0 && tid < 4) meta[tid] = 0;   // cnt, Mtop, anyv, done

    // Stage cr (SROWS x SCOLS) region, origin (by-5, bx-5), zero-padded.
    for (int l = tid; l < SROWS * SCOLS; l += 256) {
        int r = l / SCOLS, c = l % SCOLS;
        int gy = by - 5 + r, gx = bx - 5 + c;
        bool ok = (gy >= 0) && (gy < HH) && (gx >= 0) && (gx < WW);
        float vx = ok ? cr[gy * WW + gx] : 0.0f;
        float vy = ok ? cr[HH * WW + gy * WW + gx] : 0.0f;
        s[r][c] = make_float2(vx, vy);
    }
    __syncthreads();

    const int x = tid & 63;        // 0..63 within tile
    const int yt = tid >> 6;       // 0..3 -> output rows yt*2, yt*2+1
    // 4 independent accumulator chains (reassociated sum: safe — vote
    // perturbation ~1e-5 vs 0.3 margin to CENTER_THRESH; NMS equality only
    // compares values computed here with identical op order).
    float a0 = 0.f, b0 = 0.f, a1 = 0.f, b1 = 0.f;

    #pragma unroll
    for (int rr = 0; rr <= TT + 9; ++rr) {          // LDS row offset 0..11
        #pragma unroll
        for (int ix = 0; ix < KK; ++ix) {
            const int ox = ix - 5;
            float2 v = s[yt * TT + rr][x + ix];
            {   // t = 0 : oy = rr - 5
                const int oy = rr - 5;
                if (oy >= -RR && oy <= RR && ox * ox + oy * oy <= RR * RR) {
                    float dx = (float)ox - v.x, dy = (float)oy - v.y;
                    float sv = __builtin_amdgcn_sqrtf(dx * dx + dy * dy);
                    if (ix & 1) b0 += sv; else a0 += sv;
                }
            }
            {   // t = 1 : oy = rr - 6
                const int oy = rr - 6;
                if (oy >= -RR && oy <= RR && ox * ox + oy * oy <= RR * RR) {
                    float dx = (float)ox - v.x, dy = (float)oy - v.y;
                    float sv = __builtin_amdgcn_sqrtf(dx * dx + dy * dy);
                    if (ix & 1) b1 += sv; else a1 += sv;
                }
            }
        }
    }
    const int y0 = by + yt * TT;
    vote[y0 * WW + bx + x]       = (a0 + b0) / 81.0f + 1.0f;
    vote[(y0 + 1) * WW + bx + x] = (a1 + b1) / 81.0f + 1.0f;
}

// NMS + (last block) top-k selection fused via the last-block-done pattern.
__global__ __launch_bounds__(256) void nms_select_kernel(const float* __restrict__ vote,
                                                         float* __restrict__ cv,
                                                         int* __restrict__ ci,
                                                         int* __restrict__ meta, float ct,
                                                         float* __restrict__ selx,
                                                         float* __restrict__ sely,
                                                         float* __restrict__ out) {
    const int tid = threadIdx.x;
    int pix = blockIdx.x * 256 + tid;
    int y = pix >> 10, x = pix & (WW - 1);
    float v = vote[pix];
    float m = v;
    // index-clamp == inf-padding for a min-pool (duplicated edge values
    // cannot change the min)
    #pragma unroll
    for (int dy = -3; dy <= 3; ++dy) {
        int yy = min(max(y + dy, 0), HH - 1);
        const float* row = vote + yy * WW;
        #pragma unroll
        for (int dx = -3; dx <= 3; ++dx) {
            int xx = min(max(x + dx, 0), WW - 1);
            m = fminf(m, row[xx]);
        }
    }
    if (v == m && v < ct) {
        int s = atomicAdd(&meta[0], 1);
        if (s < MAXC) { cv[s] = v; ci[s] = pix; }
    }

    // ---- last-block-done handshake (deadlock-free: nobody spins) ----
    __syncthreads();
    __threadfence();                       // publish cv/ci/meta[0] device-wide
    __shared__ int s_last;
    if (tid == 0) {
        int t = atomicAdd(&meta[3], 1);
        s_last = (t == (int)gridDim.x - 1);
    }
    __syncthreads();
    if (!s_last) return;
    __threadfence();                       // acquire: see all blocks' cv/ci

    // ---- selection phase (runs in exactly one block) ----
    __shared__ float bv[256];
    __shared__ int bi[256];
    __shared__ int s_idx[TOPK];
    __shared__ float s_val[TOPK];
    int M = meta[0];
    if (M > MAXC) M = MAXC;
    const int Mtop = (M < TOPK) ? M : TOPK;

    // k-th smallest by (val, idx) lexicographic = min over entries strictly
    // greater than the previously selected one (matches jax top_k tie-break).
    float lastv = -INFINITY;
    int lasti = -1;
    for (int k = 0; k < Mtop; ++k) {
        float bestv = INFINITY;
        int besti = 0x7fffffff;
        for (int j = tid; j < M; j += 256) {
            float cvj = cv[j];
            int cij = ci[j];
            if (cvj > lastv || (cvj == lastv && cij > lasti)) {
                if (cvj < bestv || (cvj == bestv && cij < besti)) { bestv = cvj; besti = cij; }
            }
        }
        bv[tid] = bestv; bi[tid] = besti;
        __syncthreads();
        for (int s = 128; s > 0; s >>= 1) {
            if (tid < s) {
                float ov = bv[tid + s]; int oi = bi[tid + s];
                if (ov < bv[tid] || (ov == bv[tid] && oi < bi[tid])) { bv[tid] = ov; bi[tid] = oi; }
            }
            __syncthreads();
        }
        lastv = bv[0]; lasti = bi[0];
        if (tid == 0) { s_val[k] = lastv; s_idx[k] = lasti; }
        __syncthreads();
    }

    // Parallel fill of remaining slots with the smallest non-candidate
    // indices (all non-candidates tie at -inf in top_k(-cand): ascending
    // index). rank r non-candidate index = fixed point of g = r + #{ci <= g}.
    for (int k = Mtop + tid; k < TOPK; k += 256) {
        int r = k - Mtop;
        int g = r, prev = -1;
        while (g != prev) {
            prev = g;
            int c = 0;
            for (int j = 0; j < M; ++j) c += (ci[j] <= g) ? 1 : 0;
            g = r + c;
        }
        s_idx[k] = g;
        s_val[k] = INFINITY;
    }
    if (tid == 0) {
        meta[1] = Mtop;
        meta[2] = (M > 0) ? 1 : 0;
    }
    __syncthreads();

    for (int k = tid; k < TOPK; k += 256) {
        int idx = s_idx[k];
        int cy = idx >> 10;          // idx / W
        int cx = idx & (WW - 1);     // idx % W
        out[HH * WW + 2 * k]     = (float)cy;
        out[HH * WW + 2 * k + 1] = (float)cx;
        bool valid = (k < Mtop);
        out[HH * WW + 2 * TOPK + k] = valid ? s_val[k] : 0.0f;
        selx[k] = (float)cx;
        sely[k] = (float)cy;
    }
}

__global__ __launch_bounds__(256) void inst_kernel(const float* __restrict__ fg,
                                                   const float* __restrict__ cr,
                                                   const float* __restrict__ selx,
                                                   const float* __restrict__ sely,
                                                   const int* __restrict__ meta,
                                                   float* __restrict__ out) {
    int pix = blockIdx.x * 256 + threadIdx.x;
    int y = pix >> 10, x = pix & (WW - 1);
    const int Mtop = meta[1];
    const int anyv = meta[2];
    float res = 0.0f;
    if (anyv && fg[pix] >= 0.5f) {
        float px = (float)(x + 1) - cr[pix];
        float py = (float)(y + 1) - cr[HH * WW + pix];
        float best = INFINITY;
        int bk = 0;
        for (int k = 0; k < Mtop; ++k) {
            float ddx = px - selx[k];
            float ddy = py - sely[k];
            float d = ddx * ddx + ddy * ddy;
            if (d < best) { best = d; bk = k; }  // strict < keeps first occurrence
        }
        res = (float)(bk + 1);
    }
    out[pix] = res;
}

extern "C" void kernel_launch(void* const* d_in, const int* in_sizes, int n_in,
                              void* d_out, int out_size, void* d_ws, size_t ws_size,
                              hipStream_t stream) {
    const float* fg = (const float*)d_in[0];
    const float* cr = (const float*)d_in[1];
    float* out = (float*)d_out;

    char* ws = (char*)d_ws;
    int* meta = (int*)ws;
    float* vote = (float*)(ws + 64);
    float* cv = (float*)(ws + 64 + 4 * HH * WW);
    int* ci = (int*)(ws + 64 + 4 * HH * WW + 4 * MAXC);
    float* selx = (float*)(ws + 64 + 4 * HH * WW + 8 * MAXC);
    float* sely = selx + TOPK;

    // CENTER_THRESH = mean circle distance + 0.5
    double s = 0.0;
    int n = 0;
    for (int iy = 0; iy < KK; ++iy)
        for (int ix = 0; ix < KK; ++ix) {
            double dx = ix - RR, dy = iy - RR;
            double d = sqrt(dx * dx + dy * dy);
            if (d <= (double)RR) { s += d; n++; }
        }
    float ct = (float)(s / n + 0.5);

    dim3 vgrid(WW / BW, HH / BH);   // 16 x 64 = 1024 blocks
    vote_kernel<<<vgrid, 256, 0, stream>>>(cr, vote, meta);
    nms_select_kernel<<<(HH * WW) / 256, 256, 0, stream>>>(vote, cv, ci, meta, ct,
                                                           selx, sely, out);
    inst_kernel<<<(HH * WW) / 256, 256, 0, stream>>>(fg, cr, selx, sely, meta, out);
}

// Round 5
// 23.718 us; speedup vs baseline: 6.5249x; 6.5249x over previous
//
#include <hip/hip_runtime.h>
#include <math.h>

#define HH 512
#define WW 1024
#define RR 5
#define KK 11
#define TOPK 200
#define MAXC 16384

// ---- vote tile: 64 wide x 16 tall, 256 threads, 4 output rows per thread
#define BW 64
#define BH 16
#define TT 4
#define SROWS (BH + 10)   // 26 staged rows
#define SCOLS (BW + 10)   // 74 staged cols

// ws layout (bytes):
// [0..63]          : meta ints: meta[0]=cnt, meta[1]=Mtop, meta[2]=anyv
// [64 ..)          : vote float[H*W]
// [64+4*HW ..)     : cv float[MAXC]
// [.. +4*MAXC ..)  : ci int[MAXC]
// [.. +4*MAXC ..)  : selx float[TOPK], sely float[TOPK]

__global__ __launch_bounds__(256) void vote_kernel(const float* __restrict__ cr,
                                                   float* __restrict__ vote,
                                                   int* __restrict__ meta) {
    __shared__ float2 s[SROWS][SCOLS + 2];   // row stride 76 float2
    const int tid = threadIdx.x;
    const int bx = blockIdx.x * BW, by = blockIdx.y * BH;

    if (bx == 0 && by == 0 && tid < 4) meta[tid] = 0;   // cnt, Mtop, anyv, spare

    // Stage cr (SROWS x SCOLS) region, origin (by-5, bx-5), zero-padded.
    for (int l = tid; l < SROWS * SCOLS; l += 256) {
        int r = l / SCOLS, c = l % SCOLS;
        int gy = by - 5 + r, gx = bx - 5 + c;
        bool ok = (gy >= 0) && (gy < HH) && (gx >= 0) && (gx < WW);
        float vx = ok ? cr[gy * WW + gx] : 0.0f;
        float vy = ok ? cr[HH * WW + gy * WW + gx] : 0.0f;
        s[r][c] = make_float2(vx, vy);
    }
    __syncthreads();

    const int x = tid & 63;        // 0..63 within tile
    const int yt = tid >> 6;       // 0..3 -> output rows yt*4 .. yt*4+3
    // 2 accumulator chains per output row (reassociated sum: safe — vote
    // perturbation ~1e-5 vs ~0.3 margin to CENTER_THRESH; NMS equality only
    // compares values computed here with identical op order).
    float a[TT] = {0.f, 0.f, 0.f, 0.f};
    float b[TT] = {0.f, 0.f, 0.f, 0.f};

    #pragma unroll
    for (int rr = 0; rr < TT + 10; ++rr) {          // staged row offset 0..13
        #pragma unroll
        for (int ix = 0; ix < KK; ++ix) {
            const int ox = ix - 5;
            // which of the 4 output rows sample this staged point?
            bool any = false;
            #pragma unroll
            for (int t = 0; t < TT; ++t) {
                const int oy = rr - 5 - t;
                if (oy >= -RR && oy <= RR && ox * ox + oy * oy <= RR * RR) any = true;
            }
            if (!any) continue;                      // compile-time elision
            float2 v = s[yt * TT + rr][x + ix];
            #pragma unroll
            for (int t = 0; t < TT; ++t) {
                const int oy = rr - 5 - t;
                if (oy >= -RR && oy <= RR && ox * ox + oy * oy <= RR * RR) {
                    float dx = (float)ox - v.x;      // dx/dx^2 CSE'd across t
                    float dy = (float)oy - v.y;
                    float sv = __builtin_amdgcn_sqrtf(fmaf(dy, dy, dx * dx));
                    if (ix & 1) b[t] += sv; else a[t] += sv;
                }
            }
        }
    }
    const int y0 = by + yt * TT;
    #pragma unroll
    for (int t = 0; t < TT; ++t)
        vote[(y0 + t) * WW + bx + x] = (a[t] + b[t]) / 81.0f + 1.0f;
}

// Separable 7x7 min-pool NMS: each thread owns 4 pixels in a column.
// 10 row-mins shared across the 4 outputs; index-clamp == inf-padding
// (duplicated edge values are members of the true window, can't change min).
__global__ __launch_bounds__(256) void nms_kernel(const float* __restrict__ vote,
                                                  float* __restrict__ cv, int* __restrict__ ci,
                                                  int* __restrict__ meta, float ct) {
    const int tid = threadIdx.x;
    const int x = blockIdx.x * 64 + (tid & 63);
    const int y0 = blockIdx.y * 16 + (tid >> 6) * 4;

    int xc[7];
    #pragma unroll
    for (int d = 0; d < 7; ++d) xc[d] = min(max(x + d - 3, 0), WW - 1);

    float r[10], c[4];
    #pragma unroll
    for (int j = 0; j < 10; ++j) {
        int yy = min(max(y0 + j - 3, 0), HH - 1);
        const float* row = vote + yy * WW;
        float m0 = fminf(row[xc[0]], row[xc[1]]);
        float m1 = fminf(row[xc[2]], row[xc[3]]);
        float m2 = fminf(row[xc[4]], row[xc[5]]);
        float m3 = row[xc[6]];
        if (j >= 3 && j < 7) c[j - 3] = row[xc[3]];   // center value (xc[3]==x)
        r[j] = fminf(fminf(m0, m1), fminf(m2, m3));
    }
    // vertical: out_t = min(r[t..t+6]) via shared pairwise tree
    float p[9], q4[7];
    #pragma unroll
    for (int j = 0; j < 9; ++j) p[j] = fminf(r[j], r[j + 1]);
    #pragma unroll
    for (int j = 0; j < 7; ++j) q4[j] = fminf(p[j], p[j + 2]);
    #pragma unroll
    for (int t = 0; t < 4; ++t) {
        float m = fminf(q4[t], q4[t + 3]);
        float v = c[t];
        if (v == m && v < ct) {
            int s = atomicAdd(&meta[0], 1);
            if (s < MAXC) { cv[s] = v; ci[s] = (y0 + t) * WW + x; }
        }
    }
}

__global__ __launch_bounds__(256) void select_kernel(const float* __restrict__ cv,
                                                     const int* __restrict__ ci,
                                                     int* __restrict__ meta,
                                                     float* __restrict__ selx,
                                                     float* __restrict__ sely,
                                                     float* __restrict__ out) {
    __shared__ float bv[256];
    __shared__ int bi[256];
    __shared__ int s_idx[TOPK];
    __shared__ float s_val[TOPK];
    const int tid = threadIdx.x;
    int M = meta[0];
    if (M > MAXC) M = MAXC;
    const int Mtop = (M < TOPK) ? M : TOPK;

    // k-th smallest by (val, idx) lexicographic = min over entries strictly
    // greater than the previously selected one (matches jax top_k tie-break).
    float lastv = -INFINITY;
    int lasti = -1;
    for (int k = 0; k < Mtop; ++k) {
        float bestv = INFINITY;
        int besti = 0x7fffffff;
        for (int j = tid; j < M; j += 256) {
            float cvj = cv[j];
            int cij = ci[j];
            if (cvj > lastv || (cvj == lastv && cij > lasti)) {
                if (cvj < bestv || (cvj == bestv && cij < besti)) { bestv = cvj; besti = cij; }
            }
        }
        bv[tid] = bestv; bi[tid] = besti;
        __syncthreads();
        for (int s = 128; s > 0; s >>= 1) {
            if (tid < s) {
                float ov = bv[tid + s]; int oi = bi[tid + s];
                if (ov < bv[tid] || (ov == bv[tid] && oi < bi[tid])) { bv[tid] = ov; bi[tid] = oi; }
            }
            __syncthreads();
        }
        lastv = bv[0]; lasti = bi[0];
        if (tid == 0) { s_val[k] = lastv; s_idx[k] = lasti; }
        __syncthreads();
    }

    // Parallel fill of remaining slots with the smallest non-candidate
    // indices (all non-candidates tie at -inf in top_k(-cand): ascending
    // index). rank r non-candidate index = fixed point of g = r + #{ci <= g}.
    for (int k = Mtop + tid; k < TOPK; k += 256) {
        int r = k - Mtop;
        int g = r, prev = -1;
        while (g != prev) {
            prev = g;
            int cnt = 0;
            for (int j = 0; j < M; ++j) cnt += (ci[j] <= g) ? 1 : 0;
            g = r + cnt;
        }
        s_idx[k] = g;
        s_val[k] = INFINITY;
    }
    if (tid == 0) {
        meta[1] = Mtop;
        meta[2] = (M > 0) ? 1 : 0;
    }
    __syncthreads();

    for (int k = tid; k < TOPK; k += 256) {
        int idx = s_idx[k];
        int cy = idx >> 10;          // idx / W
        int cx = idx & (WW - 1);     // idx % W
        out[HH * WW + 2 * k]     = (float)cy;
        out[HH * WW + 2 * k + 1] = (float)cx;
        bool valid = (k < Mtop);
        out[HH * WW + 2 * TOPK + k] = valid ? s_val[k] : 0.0f;
        selx[k] = (float)cx;
        sely[k] = (float)cy;
    }
}

// 4 pixels per thread, float4 I/O. grid 512 blocks.
__global__ __launch_bounds__(256) void inst_kernel(const float* __restrict__ fg,
                                                   const float* __restrict__ cr,
                                                   const float* __restrict__ selx,
                                                   const float* __restrict__ sely,
                                                   const int* __restrict__ meta,
                                                   float* __restrict__ out) {
    int idx4 = blockIdx.x * 256 + threadIdx.x;     // float4 index
    const int Mtop = meta[1];
    const int anyv = meta[2];
    float4 o = make_float4(0.f, 0.f, 0.f, 0.f);
    if (anyv) {
        int pix0 = idx4 * 4;
        int y = pix0 >> 10;
        float4 f = ((const float4*)fg)[idx4];
        float4 cx0 = ((const float4*)cr)[idx4];
        float4 cy0 = ((const float4*)(cr + HH * WW))[idx4];
        float fgv[4] = {f.x, f.y, f.z, f.w};
        float crx[4] = {cx0.x, cx0.y, cx0.z, cx0.w};
        float cry[4] = {cy0.x, cy0.y, cy0.z, cy0.w};
        float res[4];
        #pragma unroll
        for (int t = 0; t < 4; ++t) {
            res[t] = 0.f;
            if (fgv[t] >= 0.5f) {
                int x = (pix0 + t) & (WW - 1);
                float px = (float)(x + 1) - crx[t];
                float py = (float)(y + 1) - cry[t];
                float best = INFINITY;
                int bk = 0;
                for (int k = 0; k < Mtop; ++k) {
                    float ddx = px - selx[k];
                    float ddy = py - sely[k];
                    float d = ddx * ddx + ddy * ddy;
                    if (d < best) { best = d; bk = k; }  // first-occurrence tie-break
                }
                res[t] = (float)(bk + 1);
            }
        }
        o = make_float4(res[0], res[1], res[2], res[3]);
    }
    ((float4*)out)[idx4] = o;
}

extern "C" void kernel_launch(void* const* d_in, const int* in_sizes, int n_in,
                              void* d_out, int out_size, void* d_ws, size_t ws_size,
                              hipStream_t stream) {
    const float* fg = (const float*)d_in[0];
    const float* cr = (const float*)d_in[1];
    float* out = (float*)d_out;

    char* ws = (char*)d_ws;
    int* meta = (int*)ws;
    float* vote = (float*)(ws + 64);
    float* cv = (float*)(ws + 64 + 4 * HH * WW);
    int* ci = (int*)(ws + 64 + 4 * HH * WW + 4 * MAXC);
    float* selx = (float*)(ws + 64 + 4 * HH * WW + 8 * MAXC);
    float* sely = selx + TOPK;

    // CENTER_THRESH = mean circle distance + 0.5
    double s = 0.0;
    int n = 0;
    for (int iy = 0; iy < KK; ++iy)
        for (int ix = 0; ix < KK; ++ix) {
            double dx = ix - RR, dy = iy - RR;
            double d = sqrt(dx * dx + dy * dy);
            if (d <= (double)RR) { s += d; n++; }
        }
    float ct = (float)(s / n + 0.5);

    dim3 vgrid(WW / BW, HH / BH);        // 16 x 32 = 512 blocks
    vote_kernel<<<vgrid, 256, 0, stream>>>(cr, vote, meta);
    dim3 ngrid(WW / 64, HH / 16);        // 16 x 32 = 512 blocks
    nms_kernel<<<ngrid, 256, 0, stream>>>(vote, cv, ci, meta, ct);
    select_kernel<<<1, 256, 0, stream>>>(cv, ci, meta, selx, sely, out);
    inst_kernel<<<(HH * WW / 4) / 256, 256, 0, stream>>>(fg, cr, selx, sely, meta, out);
}

// Round 6
// 22.468 us; speedup vs baseline: 6.8881x; 1.0557x over previous
//
#include <hip/hip_runtime.h>
#include <math.h>

#define HH 512
#define WW 1024
#define RR 5
#define KK 11
#define TOPK 200
#define MAXC 16384

// ---- vote tile: 64 wide x 16 tall, 256 threads, 4 output rows per thread
#define BW 64
#define BH 16
#define TT 4
#define SROWS (BH + 10)   // 26 staged rows
#define SCOLS (BW + 10)   // 74 staged cols

// ws layout (bytes):
// [0..63]          : meta ints: meta[0]=cnt
// [64 ..)          : vote float[H*W]
// [64+4*HW ..)     : cv float[MAXC]
// [.. +4*MAXC ..)  : ci int[MAXC]

__global__ __launch_bounds__(256) void vote_kernel(const float* __restrict__ cr,
                                                   float* __restrict__ vote,
                                                   int* __restrict__ meta) {
    __shared__ float2 s[SROWS][SCOLS + 2];   // row stride 76 float2
    const int tid = threadIdx.x;
    const int bx = blockIdx.x * BW, by = blockIdx.y * BH;

    if (bx == 0 && by == 0 && tid < 4) meta[tid] = 0;

    // Stage cr (SROWS x SCOLS) region, origin (by-5, bx-5), zero-padded.
    for (int l = tid; l < SROWS * SCOLS; l += 256) {
        int r = l / SCOLS, c = l % SCOLS;
        int gy = by - 5 + r, gx = bx - 5 + c;
        bool ok = (gy >= 0) && (gy < HH) && (gx >= 0) && (gx < WW);
        float vx = ok ? cr[gy * WW + gx] : 0.0f;
        float vy = ok ? cr[HH * WW + gy * WW + gx] : 0.0f;
        s[r][c] = make_float2(vx, vy);
    }
    __syncthreads();

    const int x = tid & 63;        // 0..63 within tile
    const int yt = tid >> 6;       // 0..3 -> output rows yt*4 .. yt*4+3
    // 2 accumulator chains per output row (reassociated sum: safe — vote
    // perturbation ~1e-5 vs ~0.3 margin to CENTER_THRESH; NMS equality only
    // compares values computed here with identical op order).
    float a[TT] = {0.f, 0.f, 0.f, 0.f};
    float b[TT] = {0.f, 0.f, 0.f, 0.f};

    #pragma unroll
    for (int rr = 0; rr < TT + 10; ++rr) {          // staged row offset 0..13
        #pragma unroll
        for (int ix = 0; ix < KK; ++ix) {
            const int ox = ix - 5;
            // which of the 4 output rows sample this staged point?
            bool any = false;
            #pragma unroll
            for (int t = 0; t < TT; ++t) {
                const int oy = rr - 5 - t;
                if (oy >= -RR && oy <= RR && ox * ox + oy * oy <= RR * RR) any = true;
            }
            if (!any) continue;                      // compile-time elision
            float2 v = s[yt * TT + rr][x + ix];
            #pragma unroll
            for (int t = 0; t < TT; ++t) {
                const int oy = rr - 5 - t;
                if (oy >= -RR && oy <= RR && ox * ox + oy * oy <= RR * RR) {
                    float dx = (float)ox - v.x;      // dx/dx^2 CSE'd across t
                    float dy = (float)oy - v.y;
                    float sv = __builtin_amdgcn_sqrtf(fmaf(dy, dy, dx * dx));
                    if (ix & 1) b[t] += sv; else a[t] += sv;
                }
            }
        }
    }
    const int y0 = by + yt * TT;
    #pragma unroll
    for (int t = 0; t < TT; ++t)
        vote[(y0 + t) * WW + bx + x] = (a[t] + b[t]) / 81.0f + 1.0f;
}

// Separable 7x7 min-pool NMS: each thread owns 4 pixels in a column.
// 10 row-mins shared across the 4 outputs; index-clamp == inf-padding
// (duplicated edge values are members of the true window, can't change min).
__global__ __launch_bounds__(256) void nms_kernel(const float* __restrict__ vote,
                                                  float* __restrict__ cv, int* __restrict__ ci,
                                                  int* __restrict__ meta, float ct) {
    const int tid = threadIdx.x;
    const int x = blockIdx.x * 64 + (tid & 63);
    const int y0 = blockIdx.y * 16 + (tid >> 6) * 4;

    int xc[7];
    #pragma unroll
    for (int d = 0; d < 7; ++d) xc[d] = min(max(x + d - 3, 0), WW - 1);

    float r[10], c[4];
    #pragma unroll
    for (int j = 0; j < 10; ++j) {
        int yy = min(max(y0 + j - 3, 0), HH - 1);
        const float* row = vote + yy * WW;
        float m0 = fminf(row[xc[0]], row[xc[1]]);
        float m1 = fminf(row[xc[2]], row[xc[3]]);
        float m2 = fminf(row[xc[4]], row[xc[5]]);
        float m3 = row[xc[6]];
        if (j >= 3 && j < 7) c[j - 3] = row[xc[3]];   // center value (xc[3]==x)
        r[j] = fminf(fminf(m0, m1), fminf(m2, m3));
    }
    // vertical: out_t = min(r[t..t+6]) via shared pairwise tree
    float p[9], q4[7];
    #pragma unroll
    for (int j = 0; j < 9; ++j) p[j] = fminf(r[j], r[j + 1]);
    #pragma unroll
    for (int j = 0; j < 7; ++j) q4[j] = fminf(p[j], p[j + 2]);
    #pragma unroll
    for (int t = 0; t < 4; ++t) {
        float m = fminf(q4[t], q4[t + 3]);
        float v = c[t];
        if (v == m && v < ct) {
            int s = atomicAdd(&meta[0], 1);
            if (s < MAXC) { cv[s] = v; ci[s] = (y0 + t) * WW + x; }
        }
    }
}

// Selection (replicated per block, cheap when M small) + instance assignment.
// Cross-kernel visibility of cv/ci/meta: same-stream kernel ordering.
__global__ __launch_bounds__(256) void inst_select_kernel(const float* __restrict__ fg,
                                                          const float* __restrict__ cr,
                                                          const float* __restrict__ cv,
                                                          const int* __restrict__ ci,
                                                          const int* __restrict__ meta,
                                                          float* __restrict__ out) {
    __shared__ float bv[256];
    __shared__ int bi[256];
    __shared__ int s_idx[TOPK];
    __shared__ float s_val[TOPK];
    __shared__ float s_selx[TOPK];
    __shared__ float s_sely[TOPK];
    const int tid = threadIdx.x;
    int M = meta[0];
    if (M > MAXC) M = MAXC;
    const int Mtop = (M < TOPK) ? M : TOPK;

    // k-th smallest by (val, idx) lexicographic = min over entries strictly
    // greater than the previously selected one (matches jax top_k tie-break).
    float lastv = -INFINITY;
    int lasti = -1;
    for (int k = 0; k < Mtop; ++k) {
        float bestv = INFINITY;
        int besti = 0x7fffffff;
        for (int j = tid; j < M; j += 256) {
            float cvj = cv[j];
            int cij = ci[j];
            if (cvj > lastv || (cvj == lastv && cij > lasti)) {
                if (cvj < bestv || (cvj == bestv && cij < besti)) { bestv = cvj; besti = cij; }
            }
        }
        bv[tid] = bestv; bi[tid] = besti;
        __syncthreads();
        for (int s = 128; s > 0; s >>= 1) {
            if (tid < s) {
                float ov = bv[tid + s]; int oi = bi[tid + s];
                if (ov < bv[tid] || (ov == bv[tid] && oi < bi[tid])) { bv[tid] = ov; bi[tid] = oi; }
            }
            __syncthreads();
        }
        lastv = bv[0]; lasti = bi[0];
        if (tid == 0) { s_val[k] = lastv; s_idx[k] = lasti; }
        __syncthreads();
    }

    // Parallel fill of remaining slots with the smallest non-candidate
    // indices (all non-candidates tie at -inf in top_k(-cand): ascending
    // index). rank r non-candidate index = fixed point of g = r + #{ci <= g}.
    for (int k = Mtop + tid; k < TOPK; k += 256) {
        int r = k - Mtop;
        int g = r, prev = -1;
        while (g != prev) {
            prev = g;
            int cnt = 0;
            for (int j = 0; j < M; ++j) cnt += (ci[j] <= g) ? 1 : 0;
            g = r + cnt;
        }
        s_idx[k] = g;
        s_val[k] = INFINITY;
    }
    __syncthreads();

    for (int k = tid; k < TOPK; k += 256) {
        int idx = s_idx[k];
        s_sely[k] = (float)(idx >> 10);       // idx / W
        s_selx[k] = (float)(idx & (WW - 1));  // idx % W
    }
    __syncthreads();

    // block 0 writes coords + cerr outputs
    if (blockIdx.x == 0) {
        for (int k = tid; k < TOPK; k += 256) {
            out[HH * WW + 2 * k]     = s_sely[k];
            out[HH * WW + 2 * k + 1] = s_selx[k];
            out[HH * WW + 2 * TOPK + k] = (k < Mtop) ? s_val[k] : 0.0f;
        }
    }

    // ---- instance assignment: 4 pixels per thread, float4 I/O ----
    int idx4 = blockIdx.x * 256 + tid;     // float4 index
    float4 o = make_float4(0.f, 0.f, 0.f, 0.f);
    if (M > 0) {
        int pix0 = idx4 * 4;
        int y = pix0 >> 10;
        float4 f = ((const float4*)fg)[idx4];
        float4 cx0 = ((const float4*)cr)[idx4];
        float4 cy0 = ((const float4*)(cr + HH * WW))[idx4];
        float fgv[4] = {f.x, f.y, f.z, f.w};
        float crx[4] = {cx0.x, cx0.y, cx0.z, cx0.w};
        float cry[4] = {cy0.x, cy0.y, cy0.z, cy0.w};
        float res[4];
        #pragma unroll
        for (int t = 0; t < 4; ++t) {
            res[t] = 0.f;
            if (fgv[t] >= 0.5f) {
                int x = (pix0 + t) & (WW - 1);
                float px = (float)(x + 1) - crx[t];
                float py = (float)(y + 1) - cry[t];
                float best = INFINITY;
                int bk = 0;
                for (int k = 0; k < Mtop; ++k) {
                    float ddx = px - s_selx[k];
                    float ddy = py - s_sely[k];
                    float d = ddx * ddx + ddy * ddy;
                    if (d < best) { best = d; bk = k; }  // first-occurrence tie-break
                }
                res[t] = (float)(bk + 1);
            }
        }
        o = make_float4(res[0], res[1], res[2], res[3]);
    }
    ((float4*)out)[idx4] = o;
}

extern "C" void kernel_launch(void* const* d_in, const int* in_sizes, int n_in,
                              void* d_out, int out_size, void* d_ws, size_t ws_size,
                              hipStream_t stream) {
    const float* fg = (const float*)d_in[0];
    const float* cr = (const float*)d_in[1];
    float* out = (float*)d_out;

    char* ws = (char*)d_ws;
    int* meta = (int*)ws;
    float* vote = (float*)(ws + 64);
    float* cv = (float*)(ws + 64 + 4 * HH * WW);
    int* ci = (int*)(ws + 64 + 4 * HH * WW + 4 * MAXC);

    // CENTER_THRESH = mean circle distance + 0.5
    double s = 0.0;
    int n = 0;
    for (int iy = 0; iy < KK; ++iy)
        for (int ix = 0; ix < KK; ++ix) {
            double dx = ix - RR, dy = iy - RR;
            double d = sqrt(dx * dx + dy * dy);
            if (d <= (double)RR) { s += d; n++; }
        }
    float ct = (float)(s / n + 0.5);

    dim3 vgrid(WW / BW, HH / BH);        // 16 x 32 = 512 blocks
    vote_kernel<<<vgrid, 256, 0, stream>>>(cr, vote, meta);
    dim3 ngrid(WW / 64, HH / 16);        // 16 x 32 = 512 blocks
    nms_kernel<<<ngrid, 256, 0, stream>>>(vote, cv, ci, meta, ct);
    inst_select_kernel<<<(HH * WW / 4) / 256, 256, 0, stream>>>(fg, cr, cv, ci, meta, out);
}